// Round 6
// baseline (918.049 us; speedup 1.0000x reference)
//
#include <hip/hip_runtime.h>

#define H_ 128
#define T_ 1024
#define B_ 512
#define I_ 13
#define LOG2E 1.4426950408889634f

typedef _Float16 half8 __attribute__((ext_vector_type(8)));
typedef float float4_ __attribute__((ext_vector_type(4)));

static __device__ __forceinline__ float fast_rcp(float v) {
  return __builtin_amdgcn_rcpf(v);
}
static __device__ __forceinline__ float fast_exp2(float v) {
  return __builtin_amdgcn_exp2f(v);
}
static __device__ __forceinline__ float sigmoid_f(float v) {
  return fast_rcp(1.0f + fast_exp2(-LOG2E * v));
}
static __device__ __forceinline__ float tanh_f(float v) {
  return 2.0f * fast_rcp(1.0f + fast_exp2(-2.0f * LOG2E * v)) - 1.0f;
}

// R11 = R10 (830us) + two serial-path cuts:
//  (1) A-row duplication: load h/x into A rows 8,12 as copies of rows 0,4
//      (aload lanes n16 in {0,4,8,12}). D rows 8,12 then duplicate rows
//      0,4, so lanes 32-63 read their gate values LOCALLY:
//      gv = lane<32 ? acc[2g][0] : acc[2g+1][0]. Removes 4 ds_bpermute
//      LDS round-trips from the activation path. Zero extra MFMA cost
//      (the dup rows ride inside MFMAs already issued).
//  (2) bias-seed + x-preacc moved AFTER the af ds_read issue (they are
//      af-independent): ~155cy of MFMA issue covers the ~120cy LDS read
//      latency, instead of delaying barrier arrival (R10 placement).
// Structure: 256 WGs x 4 waves, 2 rows/WG, 1 wave/SIMD, weights
// VGPR-resident, zero vector-memory ops in the loop.
__global__ __launch_bounds__(256, 1) void lstm_fused(
    const float* __restrict__ x, const float* __restrict__ Wih,
    const float* __restrict__ Whh, const float* __restrict__ bih,
    const float* __restrict__ bhh, const float* __restrict__ Wfc,
    const float* __restrict__ bfc, float* __restrict__ out)
{
  // 64 KB: x(t) for both rows (f16), slots 13..15 zero (pad to k-chunk)
  __shared__ __align__(16) _Float16 xlds[T_][2][16];
  // 64 KB: logits ring, slot t holds logits for output row t (cols 0..6)
  __shared__ __align__(16) float lgring[T_][2][8];
  // 1.3 KB: double-buffered h (cols 0..127 used; stride 168 halfs)
  __shared__ __align__(16) _Float16 abuf[2][2][168];

  const int tid  = threadIdx.x;
  const int wave = tid >> 6;      // 0..3
  const int lane = tid & 63;
  const int n16  = lane & 15;
  const int quad = lane >> 4;
  const int wgb  = blockIdx.x * 2;

  // ---- W fragments: wave w owns tiles {g*8 + 2w + p : g=0..3, p=0..1} ----
  // (all 4 gates for col-groups 2w and 2w+1 -> cell update is wave-local)
  // B layout (16x16x32): lane holds B[k = quad*8 + j][n = n16]
  half8 wfrag[8][5];
  float biasv[8];
  #pragma unroll
  for (int ti = 0; ti < 8; ++ti) {
    const int g    = ti >> 1;
    const int p    = ti & 1;
    const int tile = g * 8 + 2 * wave + p;
    const int col  = tile * 16 + n16;
    biasv[ti] = bih[col] + bhh[col];
    #pragma unroll
    for (int kc = 0; kc < 5; ++kc) {
      half8 f;
      #pragma unroll
      for (int j = 0; j < 8; ++j) {
        const int k = kc * 32 + quad * 8 + j;
        float v = 0.0f;
        if (k < 128)            v = Whh[col * H_ + k];
        else if (k < 128 + I_)  v = Wih[col * I_ + (k - 128)];
        f[j] = (_Float16)v;
      }
      wfrag[ti][kc] = f;
    }
  }
  // FC tile (consumed by wave 3; loaded uniformly), k < 128 -> 4 chunks
  half8 wfc[4];
  const float biasfc = (n16 < 7) ? bfc[n16] : 0.0f;
  #pragma unroll
  for (int kc = 0; kc < 4; ++kc) {
    half8 f;
    #pragma unroll
    for (int j = 0; j < 8; ++j) {
      const int k = kc * 32 + quad * 8 + j;
      f[j] = (_Float16)((n16 < 7) ? Wfc[n16 * H_ + k] : 0.0f);
    }
    wfc[kc] = f;
  }

  // ---- phase 0: preload all x for this WG into LDS (f16), zero pads ----
  for (int idx = tid; idx < T_ * 2 * 16; idx += 256) {
    const int t  = idx >> 5;
    const int rw = (idx >> 4) & 1;
    const int ii = idx & 15;
    float v = 0.0f;
    if (ii < I_) v = x[((size_t)t * B_ + wgb + rw) * I_ + ii];
    xlds[t][rw][ii] = (_Float16)v;
  }
  for (int idx = tid; idx < 2 * 2 * 168; idx += 256)
    ((_Float16*)abuf)[idx] = (_Float16)0.0f;
  __syncthreads();

  // cell state: full wave. lane -> (row=(lane>>4)&1, col=32w+(lane>=32?16:0)+n16)
  // D rows by quad: 0->0 (b0), 1->4 (b1), 2->8 (b0 dup), 3->12 (b1 dup)
  float c_state = 0.0f;
  const int  hrow = (lane >> 4) & 1;
  const int  hcol = 32 * wave + ((lane >= 32) ? 16 : 0) + n16;
  const bool aload = (n16 & 3) == 0;   // A rows 0,4,8,12
  const int  arow  = (n16 >> 2) & 1;   // rows 0,8 <- batch 0; 4,12 <- batch 1

  half8 af[4];
  half8 af4;
  {
    half8 z;
    #pragma unroll
    for (int j = 0; j < 8; ++j) z[j] = (_Float16)0.0f;
    #pragma unroll
    for (int kc = 0; kc < 4; ++kc) af[kc] = z;
    af4 = z;
  }
  if (aload && quad < 2)
    af4 = *(const half8*)&xlds[0][arow][quad * 8];

  float4_ acc[8];
  #pragma unroll
  for (int ti = 0; ti < 8; ++ti)
    #pragma unroll
    for (int r = 0; r < 4; ++r) acc[ti][r] = 0.0f;
  float4_ accf;
  #pragma unroll
  for (int r = 0; r < 4; ++r) accf[r] = 0.0f;

  // ---- phase 1: the recurrence. No vector-memory ops in this loop. ----
  for (int t = 0; t <= T_; ++t) {
    // issue A-fragment reads first (h chunks 0..3 from abuf)
    if (aload) {
      #pragma unroll
      for (int kc = 0; kc < 4; ++kc)
        af[kc] = *(const half8*)&abuf[t & 1][arow][kc * 32 + quad * 8];
    }

    if (t < T_) {
      // bias seed + x-preacc: af-independent, ~155cy of MFMA issue that
      // covers the af ds_read latency window.
      #pragma unroll
      for (int ti = 0; ti < 8; ++ti) acc[ti][0] = biasv[ti];
      #pragma unroll
      for (int ti = 0; ti < 8; ++ti)
        acc[ti] = __builtin_amdgcn_mfma_f32_16x16x32_f16(af4, wfrag[ti][4], acc[ti], 0, 0, 0);
    }

    // FC logits (wave 3): first consumer of af; its 4-deep chain drains
    // under the gate ladder.
    if (wave == 3 && t >= 1) {
      accf[0] = biasfc;
      #pragma unroll
      for (int kc = 0; kc < 4; ++kc)
        accf = __builtin_amdgcn_mfma_f32_16x16x32_f16(af[kc], wfc[kc], accf, 0, 0, 0);
      if (lane < 32 && n16 < 7)
        lgring[t - 1][quad][n16] = accf[0];
    }

    if (t < T_) {
      // h-dependent ladder: 4 chunks (acc already holds bias + xg_t)
      #pragma unroll
      for (int kc = 0; kc < 4; ++kc) {
        #pragma unroll
        for (int ti = 0; ti < 8; ++ti)
          acc[ti] = __builtin_amdgcn_mfma_f32_16x16x32_f16(af[kc], wfrag[ti][kc], acc[ti], 0, 0, 0);
      }

      // prefetch next x-fragment (independent; hides under activations)
      if (aload && quad < 2 && t + 1 < T_)
        af4 = *(const half8*)&xlds[t + 1][arow][quad * 8];

      // cell update, FULL wave, no cross-lane ops: lanes<32 use even
      // tiles (D rows 0,4), lanes>=32 use odd tiles (dup D rows 8,12).
      float gv[4];
      #pragma unroll
      for (int g = 0; g < 4; ++g)
        gv[g] = (lane < 32) ? acc[2 * g][0] : acc[2 * g + 1][0];
      const float iv = sigmoid_f(gv[0]);
      const float fv = sigmoid_f(gv[1]);
      const float gg = tanh_f(gv[2]);
      const float ov = sigmoid_f(gv[3]);
      c_state = fv * c_state + iv * gg;
      const float hv = ov * tanh_f(c_state);
      abuf[(t + 1) & 1][hrow][hcol] = (_Float16)hv;
    }

    __syncthreads();
  }

  // ---- phase 2: softmax of all 2048 logit rows -> out ----
  for (int r = tid; r < T_ * 2; r += 256) {
    const int t = r >> 1;
    const int b = r & 1;
    float lg[7];
    float mx = -3.0e38f;
    #pragma unroll
    for (int k = 0; k < 7; ++k) {
      lg[k] = lgring[t][b][k];
      mx = fmaxf(mx, lg[k]);
    }
    float s = 0.0f;
    #pragma unroll
    for (int k = 0; k < 7; ++k) {
      lg[k] = fast_exp2(LOG2E * (lg[k] - mx));
      s += lg[k];
    }
    const float rs = fast_rcp(s);
    float* op = &out[((size_t)t * B_ + wgb + b) * 7];
    #pragma unroll
    for (int k = 0; k < 7; ++k) op[k] = lg[k] * rs;
  }
}

extern "C" void kernel_launch(void* const* d_in, const int* in_sizes, int n_in,
                              void* d_out, int out_size, void* d_ws, size_t ws_size,
                              hipStream_t stream) {
  (void)in_sizes; (void)n_in; (void)out_size; (void)d_ws; (void)ws_size;
  const float* x   = (const float*)d_in[0];
  const float* Wih = (const float*)d_in[1];
  const float* Whh = (const float*)d_in[2];
  const float* bih = (const float*)d_in[3];
  const float* bhh = (const float*)d_in[4];
  const float* Wfc = (const float*)d_in[5];
  const float* bfc = (const float*)d_in[6];
  hipLaunchKernelGGL(lstm_fused, dim3(256), dim3(256), 0, stream,
                     x, Wih, Whh, bih, bhh, Wfc, bfc, (float*)d_out);
}

// Round 7
// 787.505 us; speedup vs baseline: 1.1658x; 1.1658x over previous
//
#include <hip/hip_runtime.h>

#define H_ 128
#define T_ 1024
#define B_ 512
#define I_ 13
#define LOG2E 1.4426950408889634f

typedef _Float16 half8 __attribute__((ext_vector_type(8)));
typedef float float4_ __attribute__((ext_vector_type(4)));

static __device__ __forceinline__ float fast_rcp(float v) {
  return __builtin_amdgcn_rcpf(v);
}
static __device__ __forceinline__ float fast_exp2(float v) {
  return __builtin_amdgcn_exp2f(v);
}
static __device__ __forceinline__ float sigmoid_f(float v) {
  return fast_rcp(1.0f + fast_exp2(-LOG2E * v));
}
static __device__ __forceinline__ float tanh_f(float v) {
  return 2.0f * fast_rcp(1.0f + fast_exp2(-2.0f * LOG2E * v)) - 1.0f;
}

// R12 = R10's schedule (830us, measured-best) + R11's shuffle removal ONLY.
// R11 post-mortem: moving bias-seed+x-preacc from end-of-step (where it
// filled the activation-tail/pre-barrier MFMA-idle window) to post-barrier
// cost ~100cy/step (MfmaUtil 36->32). Reverted. The A-row duplication
// (correctness-proven in R11) is kept:
//   A rows 8,12 hold copies of rows 0,4 (aload n16&3==0, arow=(n16>>2)&1)
//   -> D rows 8,12 duplicate 0,4 -> lanes 32-63 read gate values LOCALLY
//   (cndmask) instead of 4 ds_bpermute LDS round-trips.
// Loop order (R10): af-reads -> FC(w3) -> h-ladder(4kc) -> af4-prefetch
//   -> activations -> bias-seed + x-preacc (fills tail) -> barrier.
// Structure: 256 WGs x 4 waves, 2 rows/WG, 1 wave/SIMD, weights
// VGPR-resident, zero vector-memory ops in the loop.
__global__ __launch_bounds__(256, 1) void lstm_fused(
    const float* __restrict__ x, const float* __restrict__ Wih,
    const float* __restrict__ Whh, const float* __restrict__ bih,
    const float* __restrict__ bhh, const float* __restrict__ Wfc,
    const float* __restrict__ bfc, float* __restrict__ out)
{
  // 64 KB: x(t) for both rows (f16), slots 13..15 zero (pad to k-chunk)
  __shared__ __align__(16) _Float16 xlds[T_][2][16];
  // 64 KB: logits ring, slot t holds logits for output row t (cols 0..6)
  __shared__ __align__(16) float lgring[T_][2][8];
  // 1.3 KB: double-buffered h (cols 0..127 used; stride 168 halfs)
  __shared__ __align__(16) _Float16 abuf[2][2][168];

  const int tid  = threadIdx.x;
  const int wave = tid >> 6;      // 0..3
  const int lane = tid & 63;
  const int n16  = lane & 15;
  const int quad = lane >> 4;
  const int wgb  = blockIdx.x * 2;

  // ---- W fragments: wave w owns tiles {g*8 + 2w + p : g=0..3, p=0..1} ----
  // (all 4 gates for col-groups 2w and 2w+1 -> cell update is wave-local)
  // B layout (16x16x32): lane holds B[k = quad*8 + j][n = n16]
  half8 wfrag[8][5];
  float biasv[8];
  #pragma unroll
  for (int ti = 0; ti < 8; ++ti) {
    const int g    = ti >> 1;
    const int p    = ti & 1;
    const int tile = g * 8 + 2 * wave + p;
    const int col  = tile * 16 + n16;
    biasv[ti] = bih[col] + bhh[col];
    #pragma unroll
    for (int kc = 0; kc < 5; ++kc) {
      half8 f;
      #pragma unroll
      for (int j = 0; j < 8; ++j) {
        const int k = kc * 32 + quad * 8 + j;
        float v = 0.0f;
        if (k < 128)            v = Whh[col * H_ + k];
        else if (k < 128 + I_)  v = Wih[col * I_ + (k - 128)];
        f[j] = (_Float16)v;
      }
      wfrag[ti][kc] = f;
    }
  }
  // FC tile (consumed by wave 3; loaded uniformly), k < 128 -> 4 chunks
  half8 wfc[4];
  const float biasfc = (n16 < 7) ? bfc[n16] : 0.0f;
  #pragma unroll
  for (int kc = 0; kc < 4; ++kc) {
    half8 f;
    #pragma unroll
    for (int j = 0; j < 8; ++j) {
      const int k = kc * 32 + quad * 8 + j;
      f[j] = (_Float16)((n16 < 7) ? Wfc[n16 * H_ + k] : 0.0f);
    }
    wfc[kc] = f;
  }

  // ---- phase 0: preload all x for this WG into LDS (f16), zero pads ----
  for (int idx = tid; idx < T_ * 2 * 16; idx += 256) {
    const int t  = idx >> 5;
    const int rw = (idx >> 4) & 1;
    const int ii = idx & 15;
    float v = 0.0f;
    if (ii < I_) v = x[((size_t)t * B_ + wgb + rw) * I_ + ii];
    xlds[t][rw][ii] = (_Float16)v;
  }
  for (int idx = tid; idx < 2 * 2 * 168; idx += 256)
    ((_Float16*)abuf)[idx] = (_Float16)0.0f;
  __syncthreads();

  // cell state: full wave. lane -> (row=(lane>>4)&1, col=32w+(lane>=32?16:0)+n16)
  // D rows by quad: 0->0 (b0), 1->4 (b1), 2->8 (b0 dup), 3->12 (b1 dup)
  float c_state = 0.0f;
  const int  hrow = (lane >> 4) & 1;
  const int  hcol = 32 * wave + ((lane >= 32) ? 16 : 0) + n16;
  const bool aload = (n16 & 3) == 0;   // A rows 0,4,8,12
  const int  arow  = (n16 >> 2) & 1;   // rows 0,8 <- batch 0; 4,12 <- batch 1

  half8 af[4];
  half8 af4;
  {
    half8 z;
    #pragma unroll
    for (int j = 0; j < 8; ++j) z[j] = (_Float16)0.0f;
    #pragma unroll
    for (int kc = 0; kc < 4; ++kc) af[kc] = z;
    af4 = z;
  }
  if (aload && quad < 2)
    af4 = *(const half8*)&xlds[0][arow][quad * 8];

  float4_ acc[8];
  #pragma unroll
  for (int ti = 0; ti < 8; ++ti)
    #pragma unroll
    for (int r = 0; r < 4; ++r) acc[ti][r] = 0.0f;
  float4_ accf;
  #pragma unroll
  for (int r = 0; r < 4; ++r) accf[r] = 0.0f;

  // prologue: acc = bias + xg(t=0)  (x-part pre-accumulated, off-path)
  #pragma unroll
  for (int ti = 0; ti < 8; ++ti) acc[ti][0] = biasv[ti];
  #pragma unroll
  for (int ti = 0; ti < 8; ++ti)
    acc[ti] = __builtin_amdgcn_mfma_f32_16x16x32_f16(af4, wfrag[ti][4], acc[ti], 0, 0, 0);

  // ---- phase 1: the recurrence. No vector-memory ops in this loop. ----
  for (int t = 0; t <= T_; ++t) {
    // A fragments: h chunks 0..3 from abuf
    if (aload) {
      #pragma unroll
      for (int kc = 0; kc < 4; ++kc)
        af[kc] = *(const half8*)&abuf[t & 1][arow][kc * 32 + quad * 8];
    }

    // FC logits FIRST (wave 3): depends only on af; its 4-deep chain
    // drains under the gate ladder instead of extending the barrier tail.
    if (wave == 3 && t >= 1) {
      accf[0] = biasfc;
      #pragma unroll
      for (int kc = 0; kc < 4; ++kc)
        accf = __builtin_amdgcn_mfma_f32_16x16x32_f16(af[kc], wfc[kc], accf, 0, 0, 0);
      if (lane < 32 && n16 < 7)
        lgring[t - 1][quad][n16] = accf[0];
    }

    if (t < T_) {
      // h-dependent ladder: 4 chunks (acc already holds bias + xg_t)
      #pragma unroll
      for (int kc = 0; kc < 4; ++kc) {
        #pragma unroll
        for (int ti = 0; ti < 8; ++ti)
          acc[ti] = __builtin_amdgcn_mfma_f32_16x16x32_f16(af[kc], wfrag[ti][kc], acc[ti], 0, 0, 0);
      }

      // issue next x-fragment load early (latency hides under activations)
      if (aload && quad < 2 && t + 1 < T_)
        af4 = *(const half8*)&xlds[t + 1][arow][quad * 8];

      // cell update, FULL wave, no cross-lane ops: lanes<32 use even
      // tiles (D rows 0,4), lanes>=32 use odd tiles (dup D rows 8,12).
      float gv[4];
      #pragma unroll
      for (int g = 0; g < 4; ++g)
        gv[g] = (lane < 32) ? acc[2 * g][0] : acc[2 * g + 1][0];
      const float iv = sigmoid_f(gv[0]);
      const float fv = sigmoid_f(gv[1]);
      const float gg = tanh_f(gv[2]);
      const float ov = sigmoid_f(gv[3]);
      c_state = fv * c_state + iv * gg;
      const float hv = ov * tanh_f(c_state);
      abuf[(t + 1) & 1][hrow][hcol] = (_Float16)hv;

      // re-init + x-preaccumulation for step t+1 (h-independent: fills
      // the MFMA-idle window under the activation tail / barrier wait)
      #pragma unroll
      for (int ti = 0; ti < 8; ++ti) acc[ti][0] = biasv[ti];
      #pragma unroll
      for (int ti = 0; ti < 8; ++ti)
        acc[ti] = __builtin_amdgcn_mfma_f32_16x16x32_f16(af4, wfrag[ti][4], acc[ti], 0, 0, 0);
    }

    __syncthreads();
  }

  // ---- phase 2: softmax of all 2048 logit rows -> out ----
  for (int r = tid; r < T_ * 2; r += 256) {
    const int t = r >> 1;
    const int b = r & 1;
    float lg[7];
    float mx = -3.0e38f;
    #pragma unroll
    for (int k = 0; k < 7; ++k) {
      lg[k] = lgring[t][b][k];
      mx = fmaxf(mx, lg[k]);
    }
    float s = 0.0f;
    #pragma unroll
    for (int k = 0; k < 7; ++k) {
      lg[k] = fast_exp2(LOG2E * (lg[k] - mx));
      s += lg[k];
    }
    const float rs = fast_rcp(s);
    float* op = &out[((size_t)t * B_ + wgb + b) * 7];
    #pragma unroll
    for (int k = 0; k < 7; ++k) op[k] = lg[k] * rs;
  }
}

extern "C" void kernel_launch(void* const* d_in, const int* in_sizes, int n_in,
                              void* d_out, int out_size, void* d_ws, size_t ws_size,
                              hipStream_t stream) {
  (void)in_sizes; (void)n_in; (void)out_size; (void)d_ws; (void)ws_size;
  const float* x   = (const float*)d_in[0];
  const float* Wih = (const float*)d_in[1];
  const float* Whh = (const float*)d_in[2];
  const float* bih = (const float*)d_in[3];
  const float* bhh = (const float*)d_in[4];
  const float* Wfc = (const float*)d_in[5];
  const float* bfc = (const float*)d_in[6];
  hipLaunchKernelGGL(lstm_fused, dim3(256), dim3(256), 0, stream,
                     x, Wih, Whh, bih, bhh, Wfc, bfc, (float*)d_out);
}

// Round 8
// 615.467 us; speedup vs baseline: 1.4916x; 1.2795x over previous
//
#include <hip/hip_runtime.h>

#define H_ 128
#define T_ 1024
#define B_ 512
#define I_ 13
#define LOG2E 1.4426950408889634f

typedef _Float16 half8 __attribute__((ext_vector_type(8)));
typedef float float4_ __attribute__((ext_vector_type(4)));

static __device__ __forceinline__ float fast_rcp(float v) {
  return __builtin_amdgcn_rcpf(v);
}
static __device__ __forceinline__ float fast_exp2(float v) {
  return __builtin_amdgcn_exp2f(v);
}
static __device__ __forceinline__ float sigmoid_f(float v) {
  return fast_rcp(1.0f + fast_exp2(-LOG2E * v));
}
static __device__ __forceinline__ float tanh_f(float v) {
  return 2.0f * fast_rcp(1.0f + fast_exp2(-2.0f * LOG2E * v)) - 1.0f;
}

// R13 = R12's schedule at 8 waves (2 waves/SIMD) instead of 4 (1/SIMD).
// R12 model: period 1817cy but identifiable serial components sum to only
// ~1250cy. Hypothesis: single-wave MFMA issue rate (~32cy/instr when the
// wave can't co-issue) adds ~550cy to the ladder. Two waves/SIMD halve the
// per-wave issue burden (16+4 vs 32+8 MFMAs) and interleave issue, and
// partially cover each other's ds_read/activation windows.
// Per wave: ONE col-group (4 tiles = 16 cols x 4 gates, tile = g*8+w) ->
// activation is fully lane-local (gv[g] = acc[g][0], dup A-rows 8,12 give
// quads 2,3 copies of rows 0,4 -- not even a cndmask).
// Schedule per step (R12 order, proven): af-reads -> FC(w7, af-first
// consumer) -> h-ladder(4kc x 4ti) -> af4-prefetch -> activations ->
// bias-seed + x-preacc (fills MFMA-idle tail) -> barrier.
// Structure: 256 WGs x 8 waves, 2 rows/WG, weights VGPR-resident
// (wfrag 80 VGPR/wave), zero vector-memory ops in the loop.
__global__ __launch_bounds__(512, 1) void lstm_fused(
    const float* __restrict__ x, const float* __restrict__ Wih,
    const float* __restrict__ Whh, const float* __restrict__ bih,
    const float* __restrict__ bhh, const float* __restrict__ Wfc,
    const float* __restrict__ bfc, float* __restrict__ out)
{
  // 64 KB: x(t) for both rows (f16), slots 13..15 zero (pad to k-chunk)
  __shared__ __align__(16) _Float16 xlds[T_][2][16];
  // 64 KB: logits ring, slot t holds logits for output row t (cols 0..6)
  __shared__ __align__(16) float lgring[T_][2][8];
  // 1.3 KB: double-buffered h (cols 0..127 used; stride 168 halfs)
  __shared__ __align__(16) _Float16 abuf[2][2][168];

  const int tid  = threadIdx.x;
  const int wave = tid >> 6;      // 0..7
  const int lane = tid & 63;
  const int n16  = lane & 15;
  const int quad = lane >> 4;
  const int wgb  = blockIdx.x * 2;

  // ---- W fragments: wave w owns tiles {g*8 + w : g=0..3} ----
  // (all 4 gates for col-group w -> cell update is lane-local)
  // B layout (16x16x32): lane holds B[k = quad*8 + j][n = n16]
  half8 wfrag[4][5];
  float biasv[4];
  #pragma unroll
  for (int ti = 0; ti < 4; ++ti) {
    const int tile = ti * 8 + wave;
    const int col  = tile * 16 + n16;
    biasv[ti] = bih[col] + bhh[col];
    #pragma unroll
    for (int kc = 0; kc < 5; ++kc) {
      half8 f;
      #pragma unroll
      for (int j = 0; j < 8; ++j) {
        const int k = kc * 32 + quad * 8 + j;
        float v = 0.0f;
        if (k < 128)            v = Whh[col * H_ + k];
        else if (k < 128 + I_)  v = Wih[col * I_ + (k - 128)];
        f[j] = (_Float16)v;
      }
      wfrag[ti][kc] = f;
    }
  }
  // FC tile (consumed by wave 7; loaded uniformly), k < 128 -> 4 chunks
  half8 wfc[4];
  const float biasfc = (n16 < 7) ? bfc[n16] : 0.0f;
  #pragma unroll
  for (int kc = 0; kc < 4; ++kc) {
    half8 f;
    #pragma unroll
    for (int j = 0; j < 8; ++j) {
      const int k = kc * 32 + quad * 8 + j;
      f[j] = (_Float16)((n16 < 7) ? Wfc[n16 * H_ + k] : 0.0f);
    }
    wfc[kc] = f;
  }

  // ---- phase 0: preload all x for this WG into LDS (f16), zero pads ----
  for (int idx = tid; idx < T_ * 2 * 16; idx += 512) {
    const int t  = idx >> 5;
    const int rw = (idx >> 4) & 1;
    const int ii = idx & 15;
    float v = 0.0f;
    if (ii < I_) v = x[((size_t)t * B_ + wgb + rw) * I_ + ii];
    xlds[t][rw][ii] = (_Float16)v;
  }
  for (int idx = tid; idx < 2 * 2 * 168; idx += 512)
    ((_Float16*)abuf)[idx] = (_Float16)0.0f;
  __syncthreads();

  // cell state: quad q tracks D row 4q: rows 0,8 = batch 0; 4,12 = batch 1
  // (rows 8,12 are duplicates -> quads 2,3 mirror quads 0,1)
  float c_state = 0.0f;
  const bool aload = (n16 & 3) == 0;   // A rows 0,4,8,12
  const int  arow  = (n16 >> 2) & 1;   // rows 0,8 <- b0; 4,12 <- b1

  half8 af[4];
  half8 af4;
  {
    half8 z;
    #pragma unroll
    for (int j = 0; j < 8; ++j) z[j] = (_Float16)0.0f;
    #pragma unroll
    for (int kc = 0; kc < 4; ++kc) af[kc] = z;
    af4 = z;
  }
  if (aload && quad < 2)
    af4 = *(const half8*)&xlds[0][arow][quad * 8];

  float4_ acc[4];
  #pragma unroll
  for (int ti = 0; ti < 4; ++ti)
    #pragma unroll
    for (int r = 0; r < 4; ++r) acc[ti][r] = 0.0f;
  float4_ accf;
  #pragma unroll
  for (int r = 0; r < 4; ++r) accf[r] = 0.0f;

  // prologue: acc = bias + xg(t=0)  (x-part pre-accumulated, off-path)
  #pragma unroll
  for (int ti = 0; ti < 4; ++ti) acc[ti][0] = biasv[ti];
  #pragma unroll
  for (int ti = 0; ti < 4; ++ti)
    acc[ti] = __builtin_amdgcn_mfma_f32_16x16x32_f16(af4, wfrag[ti][4], acc[ti], 0, 0, 0);

  // ---- phase 1: the recurrence. No vector-memory ops in this loop. ----
  for (int t = 0; t <= T_; ++t) {
    // A fragments: h chunks 0..3 from abuf
    if (aload) {
      #pragma unroll
      for (int kc = 0; kc < 4; ++kc)
        af[kc] = *(const half8*)&abuf[t & 1][arow][kc * 32 + quad * 8];
    }

    // FC logits FIRST (wave 7): depends only on af; its 4-deep chain
    // drains under the gate ladder instead of extending the barrier tail.
    if (wave == 7 && t >= 1) {
      accf[0] = biasfc;
      #pragma unroll
      for (int kc = 0; kc < 4; ++kc)
        accf = __builtin_amdgcn_mfma_f32_16x16x32_f16(af[kc], wfc[kc], accf, 0, 0, 0);
      if (lane < 32 && n16 < 7)
        lgring[t - 1][quad][n16] = accf[0];
    }

    if (t < T_) {
      // h-dependent ladder: 4 chunks (acc already holds bias + xg_t)
      #pragma unroll
      for (int kc = 0; kc < 4; ++kc) {
        #pragma unroll
        for (int ti = 0; ti < 4; ++ti)
          acc[ti] = __builtin_amdgcn_mfma_f32_16x16x32_f16(af[kc], wfrag[ti][kc], acc[ti], 0, 0, 0);
      }

      // issue next x-fragment load early (latency hides under activations)
      if (aload && quad < 2 && t + 1 < T_)
        af4 = *(const half8*)&xlds[t + 1][arow][quad * 8];

      // cell update, FULL wave, fully lane-local (dup D rows for quads 2,3)
      const float iv = sigmoid_f(acc[0][0]);
      const float fv = sigmoid_f(acc[1][0]);
      const float gg = tanh_f(acc[2][0]);
      const float ov = sigmoid_f(acc[3][0]);
      c_state = fv * c_state + iv * gg;
      const float hv = ov * tanh_f(c_state);
      if (lane < 32)
        abuf[(t + 1) & 1][quad][16 * wave + n16] = (_Float16)hv;

      // re-init + x-preaccumulation for step t+1 (h-independent: fills
      // the MFMA-idle window under the activation tail / barrier wait)
      #pragma unroll
      for (int ti = 0; ti < 4; ++ti) acc[ti][0] = biasv[ti];
      #pragma unroll
      for (int ti = 0; ti < 4; ++ti)
        acc[ti] = __builtin_amdgcn_mfma_f32_16x16x32_f16(af4, wfrag[ti][4], acc[ti], 0, 0, 0);
    }

    __syncthreads();
  }

  // ---- phase 2: softmax of all 2048 logit rows -> out ----
  for (int r = tid; r < T_ * 2; r += 512) {
    const int t = r >> 1;
    const int b = r & 1;
    float lg[7];
    float mx = -3.0e38f;
    #pragma unroll
    for (int k = 0; k < 7; ++k) {
      lg[k] = lgring[t][b][k];
      mx = fmaxf(mx, lg[k]);
    }
    float s = 0.0f;
    #pragma unroll
    for (int k = 0; k < 7; ++k) {
      lg[k] = fast_exp2(LOG2E * (lg[k] - mx));
      s += lg[k];
    }
    const float rs = fast_rcp(s);
    float* op = &out[((size_t)t * B_ + wgb + b) * 7];
    #pragma unroll
    for (int k = 0; k < 7; ++k) op[k] = lg[k] * rs;
  }
}

extern "C" void kernel_launch(void* const* d_in, const int* in_sizes, int n_in,
                              void* d_out, int out_size, void* d_ws, size_t ws_size,
                              hipStream_t stream) {
  (void)in_sizes; (void)n_in; (void)out_size; (void)d_ws; (void)ws_size;
  const float* x   = (const float*)d_in[0];
  const float* Wih = (const float*)d_in[1];
  const float* Whh = (const float*)d_in[2];
  const float* bih = (const float*)d_in[3];
  const float* bhh = (const float*)d_in[4];
  const float* Wfc = (const float*)d_in[5];
  const float* bfc = (const float*)d_in[6];
  hipLaunchKernelGGL(lstm_fused, dim3(256), dim3(512), 0, stream,
                     x, Wih, Whh, bih, bhh, Wfc, bfc, (float*)d_out);
}